// Round 14
// baseline (299.391 us; speedup 1.0000x reference)
//
#include <hip/hip_runtime.h>
#include <math.h>

#define NB_CLASSES 1024
#define SZ_EMBED 128
#define N_SAMPLES 262144
#define MTILE 64
#define CTILE 64
#define NBLOCKS (N_SAMPLES / MTILE)  // 4096
#define XSTRIDE 136  // bf16 elems; 272B row stride -> 2-way bank alias only (free per m136)

typedef __bf16 v8bf __attribute__((ext_vector_type(8)));
typedef float v4f __attribute__((ext_vector_type(4)));
typedef float v2f __attribute__((ext_vector_type(2)));

// exp(+-32*cos + 3.2) = exp2(46.166...*(+-cos) + 4.6166...)
#define EXP_A 46.16624130844683f
#define EXP_B 4.616624130844683f

// R22: occupancy via 2x2 wave re-tile at EQUAL per-wave efficiency.
//  - R21 post-mortem: global atomics -> main 135->149 (same-address
//    contention), non-main ~139 even with a dispatch deleted -> fixed
//    overhead confirmed. Class loop reverted to R19 base.
//  - Lever: wave = 32 rows x 32 cols (2x2 grid), two 16-class sub-strips
//    SEQUENTIAL so bfrag=16 regs transient, acc=8 per-sub-strip-local.
//    Matrix state 96 -> ~60, total ~110 -> 4 waves/SIMD (vs 3.2). Per-wave
//    MFMA/iter unchanged (16) - no R13-style efficiency loss; STAGE and
//    global traffic IDENTICAL (B from LDS).
//  - Cross-wave B sharing -> per-iter raw-barrier protocol (hazard-audited):
//    vmcnt(2) [drains own STAGE(ct); 2 newest = stores(ct-1)] -> s_barrier
//    [all STAGE(ct) done; all buf^1 reads were iter ct-1, pre-barrier] ->
//    STAGE(ct+1) into buf^1 [safe] -> compute. sched_barrier(0) pins
//    emission order so the vmcnt ledger holds.
//  - Cross-wr sums: separate partial rows (8192 x 1024, 32MB), no atomics.
//  - Tripwires: absmax!=0 = race; Occ stuck 40 = reg cap; FETCH/WRITE
//    balloon = spill.
#define SMEM_BYTES 36096

__device__ __forceinline__ unsigned short f2bf(float f) {
    union { float f; unsigned u; } v; v.f = f;
    unsigned u = v.u;
    unsigned rounding = 0x7FFFu + ((u >> 16) & 1u);
    return (unsigned short)((u + rounding) >> 16);
}
__device__ __forceinline__ float bfbits_lo(unsigned u) {
    union { unsigned u; float f; } v; v.u = u << 16; return v.f;
}
__device__ __forceinline__ float bfbits_hi(unsigned u) {
    union { unsigned u; float f; } v; v.u = u & 0xffff0000u; return v.f;
}

__global__ __launch_bounds__(256) void norm_proxies_kernel(
    const float* __restrict__ proxies, unsigned short* __restrict__ pn,
    float* __restrict__ pg) {
    // blocks 0-7 zero pos_g(1024) | negd_g(1024)
    if (blockIdx.x < 8) pg[blockIdx.x * 256 + threadIdx.x] = 0.f;
    int wv = threadIdx.x >> 6;
    int lane = threadIdx.x & 63;
    int row = blockIdx.x * 4 + wv;  // grid = 256 -> rows 0..1023
    const float* src = proxies + (size_t)row * SZ_EMBED + lane * 2;
    float2 x = *(const float2*)src;
    float ss = x.x * x.x + x.y * x.y;
    #pragma unroll
    for (int off = 32; off; off >>= 1) ss += __shfl_xor(ss, off);
    float inv = rsqrtf(ss + 1e-12f);
    unsigned pk = (unsigned)f2bf(x.x * inv) | ((unsigned)f2bf(x.y * inv) << 16);
    *(unsigned*)(pn + (size_t)row * SZ_EMBED + lane * 2) = pk;
}

__global__ __launch_bounds__(256) void main_kernel(
    const float* __restrict__ X, const int* __restrict__ T,
    const unsigned short* __restrict__ Pn,
    float* __restrict__ partial_neg, float* __restrict__ pos_g,
    float* __restrict__ negd_g) {
    __shared__ __align__(16) char smem[SMEM_BYTES];
    // layout: [0..17408) xtile (64 x 136 bf16), ALIASED by bufA after extraction
    //         [17408..18432) psum  [18432..19456) dsum  [19456..19712) tT
    //         [19712..36096) bufB (16384 B)
    unsigned short* xtile = (unsigned short*)smem;
    float (*psum)[4] = (float(*)[4])(smem + 17408);
    float (*dsum)[4] = (float(*)[4])(smem + 18432);
    int* tT = (int*)(smem + 19456);

    const int t = threadIdx.x;
    const int lane = t & 63;
    const int wv = t >> 6;
    const int quad = lane >> 4;
    const int l15 = lane & 15;
    const int wr = wv >> 1;   // sample half: rows wr*32..+31
    const int wc = wv & 1;    // class half: cols wc*32..+31 of each ct tile
    const int sample_base = blockIdx.x * MTILE;
    const int row = t >> 2, part = t & 3;  // 4 threads per sample row, 32 cols each
    const char* PnB = (const char*)Pn;

    // Stage B tile `tc` into buffer `b` (b=1 -> bufA@0, b=0 -> bufB@19712).
    // Wave wv stages rows wv*16..+15 (independent of compute assignment):
    // linear LDS dest + inverse-swizzled global source + swizzled read (#21).
#define STAGE(tc, b) do {                                                      \
        char* lb_ = smem + ((b) ? 0 : 19712) + wv * 4096;                      \
        _Pragma("unroll")                                                      \
        for (int c_ = 0; c_ < 4; ++c_) {                                       \
            int rw_ = c_ * 4 + (lane >> 4);                                    \
            const char* g_ = PnB + ((size_t)((tc) * 64 + wv * 16 + rw_)) * 256 \
                             + (((lane & 15) * 16) ^ ((rw_ & 7) << 4));        \
            __builtin_amdgcn_global_load_lds(                                  \
                (__attribute__((address_space(1))) const void*)g_,             \
                (__attribute__((address_space(3))) void*)(lb_ + c_ * 1024),    \
                16, 0, 0);                                                     \
        }                                                                      \
    } while (0)

    // issue tile-0 staging immediately (bufB, no alias); phase A barriers drain it
    STAGE(0, 0);

    // ---- phase A: load + normalize X tile into bf16 LDS; diag dot -> global atomics ----
    {
        const float4* src = (const float4*)(X + (size_t)(sample_base + row) * SZ_EMBED + part * 32);
        float4 r[8];
        float ss = 0.f;
        #pragma unroll
        for (int j = 0; j < 8; ++j) {
            r[j] = src[j];
            ss += r[j].x * r[j].x + r[j].y * r[j].y + r[j].z * r[j].z + r[j].w * r[j].w;
        }
        psum[row][part] = ss;
        if (t < MTILE) tT[t] = T[sample_base + t];
        __syncthreads();
        float inv = rsqrtf(psum[row][0] + psum[row][1] + psum[row][2] + psum[row][3] + 1e-12f);
        unsigned short* dst = xtile + row * XSTRIDE + part * 32;
        #pragma unroll
        for (int j = 0; j < 8; ++j) {
            uint2 pk;
            pk.x = (unsigned)f2bf(r[j].x * inv) | ((unsigned)f2bf(r[j].y * inv) << 16);
            pk.y = (unsigned)f2bf(r[j].z * inv) | ((unsigned)f2bf(r[j].w * inv) << 16);
            *(uint2*)(dst + j * 4) = pk;
        }
        // diag partial: dot(X[row]*inv, Pn[T[row]]) over this thread's 32 cols
        int lbl = tT[row];
        const unsigned short* prow = Pn + (size_t)lbl * SZ_EMBED + part * 32;
        float d = 0.f;
        #pragma unroll
        for (int j = 0; j < 4; ++j) {  // 4 x uint4 = 32 cols
            uint4 pv = *(const uint4*)(prow + j * 8);
            float4 xa = r[2 * j], xb = r[2 * j + 1];
            d += bfbits_lo(pv.x) * xa.x + bfbits_hi(pv.x) * xa.y;
            d += bfbits_lo(pv.y) * xa.z + bfbits_hi(pv.y) * xa.w;
            d += bfbits_lo(pv.z) * xb.x + bfbits_hi(pv.z) * xb.y;
            d += bfbits_lo(pv.w) * xb.z + bfbits_hi(pv.w) * xb.w;
        }
        dsum[row][part] = d * inv;
        __syncthreads();  // xtile + dsum ready (also drains tile-0 staging)
        if (part == 0) {
            int lbl2 = tT[row];
            float dd = dsum[row][0] + dsum[row][1] + dsum[row][2] + dsum[row][3];
            float dp = __builtin_amdgcn_exp2f(fmaf(dd, -EXP_A, EXP_B));  // exp(-a(cos-mrg))
            float dn = __builtin_amdgcn_exp2f(fmaf(dd,  EXP_A, EXP_B));  // exp(+a(cos+mrg))
            atomicAdd(&pos_g[lbl2], dp);   // only contribution to pos sums
            atomicAdd(&negd_g[lbl2], dn);  // subtracted from neg sums in finalize
        }
    }

    // ---- extract A fragments: this wave's 32 sample rows (wr half) ----
    v8bf afrag[2][4];
    #pragma unroll
    for (int ri = 0; ri < 2; ++ri)
        #pragma unroll
        for (int kc = 0; kc < 4; ++kc)
            afrag[ri][kc] = *(const v8bf*)(xtile + (wr * 32 + ri * 16 + l15) * XSTRIDE + kc * 32 + quad * 8);

    // all waves done reading xtile -> bufA (alias) may now be written.
    // Full drain before this barrier -> vmcnt=0 at class-loop entry.
    __syncthreads();

    // ---- class loop: per-iter protocol (hazard-audited):
    //   vmcnt(2)  : drains own STAGE(ct) [issued last iter]; 2 newest kept =
    //               stores(ct-1). Iter 0: nothing outstanding, passes.
    //   s_barrier : all waves' STAGE(ct) complete (each waited vmcnt first);
    //               all reads of buf^1 happened in iter ct-1, pre-barrier.
    //   STAGE(ct+1) -> buf^1 : safe to overwrite now.
    //   compute ci=0,1 sequentially (bfrag transient, acc local per ci).
    float* nrow = partial_neg + (size_t)(blockIdx.x * 2 + wr) * NB_CLASSES + wc * 32 + l15;
    const int bswz = ((l15 & 7) << 4);
    const int brow0 = (wc * 32 + l15) * 256;  // ci=0 B-row byte offset; ci=1: +4096

    #pragma unroll
    for (int ct = 0; ct < NB_CLASSES / CTILE; ++ct) {
        const int cur = ct & 1;
        asm volatile("s_waitcnt vmcnt(2)" ::: "memory");
        __builtin_amdgcn_s_barrier();
        __builtin_amdgcn_sched_barrier(0);
        if (ct < NB_CLASSES / CTILE - 1) STAGE(ct + 1, cur ^ 1);
        __builtin_amdgcn_sched_barrier(0);  // pin loads before later stores (ledger)

        const char* bbase = smem + (cur ? 0 : 19712);
        #pragma unroll
        for (int ci = 0; ci < 2; ++ci) {
            const char* bb = bbase + brow0 + ci * 4096;
            v8bf bfrag[4];
            #pragma unroll
            for (int kc = 0; kc < 4; ++kc)
                bfrag[kc] = *(const v8bf*)(bb + ((kc * 64 + quad * 16) ^ bswz));

            v4f zero = {0.f, 0.f, 0.f, 0.f};
            v4f a0 = zero, a1 = zero;
            #pragma unroll
            for (int kc = 0; kc < 4; ++kc) {
                a0 = __builtin_amdgcn_mfma_f32_16x16x32_bf16(afrag[0][kc], bfrag[kc], a0, 0, 0, 0);
                a1 = __builtin_amdgcn_mfma_f32_16x16x32_bf16(afrag[1][kc], bfrag[kc], a1, 0, 0, 0);
            }
            // epilogue: 8 exp2 (this wave's 32 rows for class wc*32+ci*16+l15),
            // packed tree, cross-quad butterfly, one 4B store per quad-0 lane.
            v2f p0, p1, p2, p3;
            p0 = (v2f){__builtin_amdgcn_exp2f(fmaf(a0[0], EXP_A, EXP_B)),
                       __builtin_amdgcn_exp2f(fmaf(a0[1], EXP_A, EXP_B))};
            p1 = (v2f){__builtin_amdgcn_exp2f(fmaf(a0[2], EXP_A, EXP_B)),
                       __builtin_amdgcn_exp2f(fmaf(a0[3], EXP_A, EXP_B))};
            p2 = (v2f){__builtin_amdgcn_exp2f(fmaf(a1[0], EXP_A, EXP_B)),
                       __builtin_amdgcn_exp2f(fmaf(a1[1], EXP_A, EXP_B))};
            p3 = (v2f){__builtin_amdgcn_exp2f(fmaf(a1[2], EXP_A, EXP_B)),
                       __builtin_amdgcn_exp2f(fmaf(a1[3], EXP_A, EXP_B))};
            p0 += p2; p1 += p3; p0 += p1;
            float v = p0.x + p0.y;
            v += __shfl_xor(v, 16);
            v += __shfl_xor(v, 32);
            if (quad == 0) nrow[ct * CTILE + ci * 16] = v;
        }
    }
#undef STAGE
}

// 256 blocks, neg only, 8192 partial rows. Block (g,q): sums rows
// [g*128, g*128+128) of class columns [q*256, q*256+256) into row g*128.
__global__ __launch_bounds__(256) void row_reduce_kernel(float* __restrict__ partial_neg) {
    const int t = threadIdx.x;
    const int g = blockIdx.x >> 2, q = blockIdx.x & 3;
    float* base = partial_neg + (size_t)g * 128 * NB_CLASSES + q * 256 + t;
    float s = 0.f;
    #pragma unroll 8
    for (int r = 0; r < 128; ++r) s += base[(size_t)r * NB_CLASSES];
    base[0] = s;
}

__global__ __launch_bounds__(256) void finalize_kernel(
    const float* __restrict__ partial_neg, const float* __restrict__ pos_g,
    const float* __restrict__ negd_g, float* __restrict__ out) {
    int t = threadIdx.x;
    // surviving neg rows: {0, 128, 256, ..., 8064} = 64 rows
    float4 ns = {0.f, 0.f, 0.f, 0.f};
    #pragma unroll 8
    for (int r = 0; r < 64; ++r) {
        float4 vn = *(const float4*)(partial_neg + (size_t)r * 128 * NB_CLASSES + 4 * t);
        ns.x += vn.x; ns.y += vn.y; ns.z += vn.z; ns.w += vn.w;
    }
    float4 nd = *(const float4*)(negd_g + 4 * t);
    ns.x -= nd.x; ns.y -= nd.y; ns.z -= nd.z; ns.w -= nd.w;
    float4 ps = *(const float4*)(pos_g + 4 * t);
    float lp_pos = log1pf(ps.x) + log1pf(ps.y) + log1pf(ps.z) + log1pf(ps.w);
    float lp_neg = log1pf(ns.x) + log1pf(ns.y) + log1pf(ns.z) + log1pf(ns.w);
    float valid = (ps.x != 0.f) + (ps.y != 0.f) + (ps.z != 0.f) + (ps.w != 0.f);
    #pragma unroll
    for (int off = 32; off; off >>= 1) {
        lp_pos += __shfl_xor(lp_pos, off);
        lp_neg += __shfl_xor(lp_neg, off);
        valid  += __shfl_xor(valid, off);
    }
    __shared__ float s[3][4];
    int wv = t >> 6, lane = t & 63;
    if (lane == 0) { s[0][wv] = lp_pos; s[1][wv] = lp_neg; s[2][wv] = valid; }
    __syncthreads();
    if (t == 0) {
        float P = s[0][0] + s[0][1] + s[0][2] + s[0][3];
        float Ng = s[1][0] + s[1][1] + s[1][2] + s[1][3];
        float V = s[2][0] + s[2][1] + s[2][2] + s[2][3];
        float pos_term = (V > 0.f) ? (P / fmaxf(V, 1.f)) : 0.f;
        float neg_term = Ng / (float)NB_CLASSES;
        out[0] = pos_term + neg_term;
        out[1] = pos_term;
        out[2] = neg_term;
    }
}

extern "C" void kernel_launch(void* const* d_in, const int* in_sizes, int n_in,
                              void* d_out, int out_size, void* d_ws, size_t ws_size,
                              hipStream_t stream) {
    const float* X = (const float*)d_in[0];
    const float* proxies = (const float*)d_in[1];
    const int* T = (const int*)d_in[2];
    float* out = (float*)d_out;

    // ws layout: Pn (256 KB) | pos_g (4 KB) | negd_g (4 KB) | partial_neg (32 MB)
    char* ws = (char*)d_ws;
    unsigned short* Pn = (unsigned short*)ws;
    float* pos_g = (float*)(ws + (size_t)NB_CLASSES * SZ_EMBED * sizeof(unsigned short));
    float* negd_g = pos_g + NB_CLASSES;
    float* partial_neg = negd_g + NB_CLASSES;

    norm_proxies_kernel<<<NB_CLASSES / 4, 256, 0, stream>>>(proxies, Pn, pos_g);
    main_kernel<<<NBLOCKS, 256, 0, stream>>>(X, T, Pn, partial_neg, pos_g, negd_g);
    row_reduce_kernel<<<256, 256, 0, stream>>>(partial_neg);
    finalize_kernel<<<1, 256, 0, stream>>>(partial_neg, pos_g, negd_g, out);
}

// Round 15
// 278.657 us; speedup vs baseline: 1.0744x; 1.0744x over previous
//
#include <hip/hip_runtime.h>
#include <math.h>

#define NB_CLASSES 1024
#define SZ_EMBED 128
#define N_SAMPLES 262144
#define MTILE 64
#define CTILE 64
#define NBLOCKS (N_SAMPLES / MTILE)  // 4096
#define XSTRIDE 136  // bf16 elems; 272B row stride -> 2-way bank alias only (free per m136)

typedef __bf16 v8bf __attribute__((ext_vector_type(8)));
typedef float v4f __attribute__((ext_vector_type(4)));
typedef float v2f __attribute__((ext_vector_type(2)));

// exp(+-32*cos + 3.2) = exp2(46.166...*(+-cos) + 4.6166...)
#define EXP_A 46.16624130844683f
#define EXP_B 4.616624130844683f

// R23: R19 base (best: 279.7 total / main 135) + two clean micro-levers.
//  - R22 post-mortem: 2x2 re-tile occupancy-neutral (LDS/wave-slot capped,
//    not reg-capped), +lockstep barrier, +bank conflicts (9.4M), +WRITE
//    (48MB) -> main 153. Family dead on 3 grounds. Reverted.
//  - Lever 1: s_setprio(1) around MFMA (T5). Never cleanly tested: R20
//    bundled it with the e_acc spill. Class loop is wave-autonomous ->
//    role-diversity regime where T5 pays (null only in lockstep).
//  - Lever 2: drop sched_barrier(0) after the vmcnt asm. Rule #18's hazard
//    is inline-asm ds_read; ours are compiler-emitted C derefs (deps
//    tracked, auto-lgkmcnt) and the "memory" clobber already orders the
//    ds_read vs the wait. The sched_barrier sealed the fully-unrolled
//    16-iter loop into 16 scheduling regions, blocking cross-iteration
//    pipelining (epilogue(ct) || ds_read(ct+1)).
//  - Both zero-footprint. If pair regresses: revert both, declare plateau.
#define SMEM_BYTES 36096

__device__ __forceinline__ unsigned short f2bf(float f) {
    union { float f; unsigned u; } v; v.f = f;
    unsigned u = v.u;
    unsigned rounding = 0x7FFFu + ((u >> 16) & 1u);
    return (unsigned short)((u + rounding) >> 16);
}
__device__ __forceinline__ float bfbits_lo(unsigned u) {
    union { unsigned u; float f; } v; v.u = u << 16; return v.f;
}
__device__ __forceinline__ float bfbits_hi(unsigned u) {
    union { unsigned u; float f; } v; v.u = u & 0xffff0000u; return v.f;
}

__global__ __launch_bounds__(256) void norm_proxies_kernel(
    const float* __restrict__ proxies, unsigned short* __restrict__ pn,
    float* __restrict__ pg) {
    // blocks 0-7 zero pos_g(1024) | negd_g(1024) - replaces memset dispatch
    if (blockIdx.x < 8) pg[blockIdx.x * 256 + threadIdx.x] = 0.f;
    int wv = threadIdx.x >> 6;
    int lane = threadIdx.x & 63;
    int row = blockIdx.x * 4 + wv;  // grid = 256 -> rows 0..1023
    const float* src = proxies + (size_t)row * SZ_EMBED + lane * 2;
    float2 x = *(const float2*)src;
    float ss = x.x * x.x + x.y * x.y;
    #pragma unroll
    for (int off = 32; off; off >>= 1) ss += __shfl_xor(ss, off);
    float inv = rsqrtf(ss + 1e-12f);
    unsigned pk = (unsigned)f2bf(x.x * inv) | ((unsigned)f2bf(x.y * inv) << 16);
    *(unsigned*)(pn + (size_t)row * SZ_EMBED + lane * 2) = pk;
}

__global__ __launch_bounds__(256) void main_kernel(
    const float* __restrict__ X, const int* __restrict__ T,
    const unsigned short* __restrict__ Pn,
    float* __restrict__ partial_neg, float* __restrict__ pos_g,
    float* __restrict__ negd_g) {
    __shared__ __align__(16) char smem[SMEM_BYTES];
    // layout: [0..17408) xtile (64 x 136 bf16), ALIASED by bufA after extraction
    //         [17408..18432) psum  [18432..19456) dsum  [19456..19712) tT
    //         [19712..36096) bufB (16384 B)
    unsigned short* xtile = (unsigned short*)smem;
    float (*psum)[4] = (float(*)[4])(smem + 17408);
    float (*dsum)[4] = (float(*)[4])(smem + 18432);
    int* tT = (int*)(smem + 19456);

    const int t = threadIdx.x;
    const int lane = t & 63;
    const int wv = t >> 6;
    const int quad = lane >> 4;
    const int l15 = lane & 15;
    const int sample_base = blockIdx.x * MTILE;
    const int row = t >> 2, part = t & 3;  // 4 threads per sample row, 32 cols each
    const char* PnB = (const char*)Pn;

    // Stage B tile `tc` into buffer `b` (b=1 -> bufA@0, b=0 -> bufB@19712).
    // Wave wv stages its own 16 rows: linear LDS dest (wave-uniform base +
    // lane*16) + inverse-swizzled global source + swizzled read (rule #21).
#define STAGE(tc, b) do {                                                      \
        char* lb_ = smem + ((b) ? 0 : 19712) + wv * 4096;                      \
        _Pragma("unroll")                                                      \
        for (int c_ = 0; c_ < 4; ++c_) {                                       \
            int rw_ = c_ * 4 + (lane >> 4);                                    \
            const char* g_ = PnB + ((size_t)((tc) * 64 + wv * 16 + rw_)) * 256 \
                             + (((lane & 15) * 16) ^ ((rw_ & 7) << 4));        \
            __builtin_amdgcn_global_load_lds(                                  \
                (__attribute__((address_space(1))) const void*)g_,             \
                (__attribute__((address_space(3))) void*)(lb_ + c_ * 1024),    \
                16, 0, 0);                                                     \
        }                                                                      \
    } while (0)

    // issue tile-0 staging immediately (bufB, no alias); phase A barriers drain it
    STAGE(0, 0);

    // ---- phase A: load + normalize X tile into bf16 LDS; diag dot -> global atomics ----
    {
        const float4* src = (const float4*)(X + (size_t)(sample_base + row) * SZ_EMBED + part * 32);
        float4 r[8];
        float ss = 0.f;
        #pragma unroll
        for (int j = 0; j < 8; ++j) {
            r[j] = src[j];
            ss += r[j].x * r[j].x + r[j].y * r[j].y + r[j].z * r[j].z + r[j].w * r[j].w;
        }
        psum[row][part] = ss;
        if (t < MTILE) tT[t] = T[sample_base + t];
        __syncthreads();
        float inv = rsqrtf(psum[row][0] + psum[row][1] + psum[row][2] + psum[row][3] + 1e-12f);
        unsigned short* dst = xtile + row * XSTRIDE + part * 32;
        #pragma unroll
        for (int j = 0; j < 8; ++j) {
            uint2 pk;
            pk.x = (unsigned)f2bf(r[j].x * inv) | ((unsigned)f2bf(r[j].y * inv) << 16);
            pk.y = (unsigned)f2bf(r[j].z * inv) | ((unsigned)f2bf(r[j].w * inv) << 16);
            *(uint2*)(dst + j * 4) = pk;
        }
        // diag partial: dot(X[row]*inv, Pn[T[row]]) over this thread's 32 cols
        int lbl = tT[row];
        const unsigned short* prow = Pn + (size_t)lbl * SZ_EMBED + part * 32;
        float d = 0.f;
        #pragma unroll
        for (int j = 0; j < 4; ++j) {  // 4 x uint4 = 32 cols
            uint4 pv = *(const uint4*)(prow + j * 8);
            float4 xa = r[2 * j], xb = r[2 * j + 1];
            d += bfbits_lo(pv.x) * xa.x + bfbits_hi(pv.x) * xa.y;
            d += bfbits_lo(pv.y) * xa.z + bfbits_hi(pv.y) * xa.w;
            d += bfbits_lo(pv.z) * xb.x + bfbits_hi(pv.z) * xb.y;
            d += bfbits_lo(pv.w) * xb.z + bfbits_hi(pv.w) * xb.w;
        }
        dsum[row][part] = d * inv;
        __syncthreads();  // xtile + dsum ready (also drains tile-0 staging)
        if (part == 0) {
            int lbl2 = tT[row];
            float dd = dsum[row][0] + dsum[row][1] + dsum[row][2] + dsum[row][3];
            float dp = __builtin_amdgcn_exp2f(fmaf(dd, -EXP_A, EXP_B));  // exp(-a(cos-mrg))
            float dn = __builtin_amdgcn_exp2f(fmaf(dd,  EXP_A, EXP_B));  // exp(+a(cos+mrg))
            atomicAdd(&pos_g[lbl2], dp);   // only contribution to pos sums
            atomicAdd(&negd_g[lbl2], dn);  // subtracted from neg sums in finalize
        }
    }

    // ---- extract A fragments into registers (resident for whole class loop) ----
    v8bf afrag[4][4];
    #pragma unroll
    for (int ri = 0; ri < 4; ++ri)
        #pragma unroll
        for (int kc = 0; kc < 4; ++kc)
            afrag[ri][kc] = *(const v8bf*)(xtile + (ri * 16 + l15) * XSTRIDE + kc * 32 + quad * 8);

    // all waves done reading xtile -> bufA (alias) may now be written.
    // Compiler emits full vmcnt drain before this barrier -> vmcnt=0 at
    // class-loop entry for every wave (STAGE(0) complete).
    __syncthreads();

    // ---- class loop: barrier-free, wave-autonomous. Per-iter VMEM ledger at
    // the wait (oldest->newest): [4 loads STAGE(ct), store(ct-1), 4 loads
    // STAGE(ct+1)]. vmcnt(5) drains exactly STAGE(ct); the store stays in
    // flight. No sched_barrier: "memory" clobber on the asm orders the
    // ds_reads; scheduler may pipeline across the unrolled iterations.
    float* nrow = partial_neg + (size_t)blockIdx.x * NB_CLASSES + wv * 16 + l15;
    const int bswz = ((l15 & 7) << 4);
    const int browoff = (wv * 16 + l15) * 256;

    #pragma unroll
    for (int ct = 0; ct < NB_CLASSES / CTILE; ++ct) {
        const int cur = ct & 1;
        if (ct < NB_CLASSES / CTILE - 1) {
            STAGE(ct + 1, cur ^ 1);
            asm volatile("s_waitcnt vmcnt(5)" ::: "memory");
        } else {
            asm volatile("s_waitcnt vmcnt(1)" ::: "memory");  // drain STAGE(15), skip store(14)
        }

        const char* bbase = smem + (cur ? 0 : 19712) + browoff;
        v8bf bfrag[4];
        #pragma unroll
        for (int kc = 0; kc < 4; ++kc)
            bfrag[kc] = *(const v8bf*)(bbase + ((kc * 64 + quad * 16) ^ bswz));

        v4f zero = {0.f, 0.f, 0.f, 0.f};
        v4f acc[4] = {zero, zero, zero, zero};
        __builtin_amdgcn_s_setprio(1);
        #pragma unroll
        for (int kc = 0; kc < 4; ++kc)
            #pragma unroll
            for (int ri = 0; ri < 4; ++ri)
                acc[ri] = __builtin_amdgcn_mfma_f32_16x16x32_bf16(afrag[ri][kc], bfrag[kc], acc[ri], 0, 0, 0);
        __builtin_amdgcn_s_setprio(0);

        // epilogue: 16 exp2, packed pairwise tree (7 v_pk_add_f32 + 1 scalar),
        // cross-quad butterfly, one 4B store per quad-0 lane.
        v2f e2[8];
        #pragma unroll
        for (int ri = 0; ri < 4; ++ri) {
            float a0 = __builtin_amdgcn_exp2f(fmaf(acc[ri][0], EXP_A, EXP_B));
            float a1 = __builtin_amdgcn_exp2f(fmaf(acc[ri][1], EXP_A, EXP_B));
            float a2 = __builtin_amdgcn_exp2f(fmaf(acc[ri][2], EXP_A, EXP_B));
            float a3 = __builtin_amdgcn_exp2f(fmaf(acc[ri][3], EXP_A, EXP_B));
            e2[ri * 2]     = (v2f){a0, a1};
            e2[ri * 2 + 1] = (v2f){a2, a3};
        }
        #pragma unroll
        for (int s2 = 4; s2; s2 >>= 1)
            #pragma unroll
            for (int j = 0; j < s2; ++j)
                e2[j] += e2[j + s2];
        float v = e2[0].x + e2[0].y;
        v += __shfl_xor(v, 16);
        v += __shfl_xor(v, 32);
        if (quad == 0) nrow[ct * CTILE] = v;
    }
#undef STAGE
}

// 256 blocks, neg only. Block (g,q): sums rows [g*64, g*64+64) of class
// columns [q*256, q*256+256) into row g*64. 256 threads = 1 KB contiguous/row.
__global__ __launch_bounds__(256) void row_reduce_kernel(float* __restrict__ partial_neg) {
    const int t = threadIdx.x;
    const int g = blockIdx.x >> 2, q = blockIdx.x & 3;
    float* base = partial_neg + (size_t)g * 64 * NB_CLASSES + q * 256 + t;
    float s = 0.f;
    #pragma unroll 8
    for (int r = 0; r < 64; ++r) s += base[(size_t)r * NB_CLASSES];
    base[0] = s;
}

__global__ __launch_bounds__(256) void finalize_kernel(
    const float* __restrict__ partial_neg, const float* __restrict__ pos_g,
    const float* __restrict__ negd_g, float* __restrict__ out) {
    int t = threadIdx.x;
    // surviving neg rows: {0, 64, 128, ..., 4032}
    float4 ns = {0.f, 0.f, 0.f, 0.f};
    #pragma unroll 8
    for (int r = 0; r < 64; ++r) {
        float4 vn = *(const float4*)(partial_neg + (size_t)r * 64 * NB_CLASSES + 4 * t);
        ns.x += vn.x; ns.y += vn.y; ns.z += vn.z; ns.w += vn.w;
    }
    float4 nd = *(const float4*)(negd_g + 4 * t);
    ns.x -= nd.x; ns.y -= nd.y; ns.z -= nd.z; ns.w -= nd.w;
    float4 ps = *(const float4*)(pos_g + 4 * t);
    float lp_pos = log1pf(ps.x) + log1pf(ps.y) + log1pf(ps.z) + log1pf(ps.w);
    float lp_neg = log1pf(ns.x) + log1pf(ns.y) + log1pf(ns.z) + log1pf(ns.w);
    float valid = (ps.x != 0.f) + (ps.y != 0.f) + (ps.z != 0.f) + (ps.w != 0.f);
    #pragma unroll
    for (int off = 32; off; off >>= 1) {
        lp_pos += __shfl_xor(lp_pos, off);
        lp_neg += __shfl_xor(lp_neg, off);
        valid  += __shfl_xor(valid, off);
    }
    __shared__ float s[3][4];
    int wv = t >> 6, lane = t & 63;
    if (lane == 0) { s[0][wv] = lp_pos; s[1][wv] = lp_neg; s[2][wv] = valid; }
    __syncthreads();
    if (t == 0) {
        float P = s[0][0] + s[0][1] + s[0][2] + s[0][3];
        float Ng = s[1][0] + s[1][1] + s[1][2] + s[1][3];
        float V = s[2][0] + s[2][1] + s[2][2] + s[2][3];
        float pos_term = (V > 0.f) ? (P / fmaxf(V, 1.f)) : 0.f;
        float neg_term = Ng / (float)NB_CLASSES;
        out[0] = pos_term + neg_term;
        out[1] = pos_term;
        out[2] = neg_term;
    }
}

extern "C" void kernel_launch(void* const* d_in, const int* in_sizes, int n_in,
                              void* d_out, int out_size, void* d_ws, size_t ws_size,
                              hipStream_t stream) {
    const float* X = (const float*)d_in[0];
    const float* proxies = (const float*)d_in[1];
    const int* T = (const int*)d_in[2];
    float* out = (float*)d_out;

    // ws layout: Pn (256 KB) | pos_g (4 KB) | negd_g (4 KB) | partial_neg (16 MB)
    char* ws = (char*)d_ws;
    unsigned short* Pn = (unsigned short*)ws;
    float* pos_g = (float*)(ws + (size_t)NB_CLASSES * SZ_EMBED * sizeof(unsigned short));
    float* negd_g = pos_g + NB_CLASSES;
    float* partial_neg = negd_g + NB_CLASSES;

    norm_proxies_kernel<<<NB_CLASSES / 4, 256, 0, stream>>>(proxies, Pn, pos_g);
    main_kernel<<<NBLOCKS, 256, 0, stream>>>(X, T, Pn, partial_neg, pos_g, negd_g);
    row_reduce_kernel<<<256, 256, 0, stream>>>(partial_neg);
    finalize_kernel<<<1, 256, 0, stream>>>(partial_neg, pos_g, negd_g, out);
}